// Round 8
// baseline (652.290 us; speedup 1.0000x reference)
//
#include <hip/hip_runtime.h>

typedef __attribute__((ext_vector_type(8))) _Float16 f16x8;
typedef __attribute__((ext_vector_type(4))) float f32x4;
typedef _Float16 f16;

#define B_    4
#define L_    4096
#define K_    12
#define ZC_   780        /* MEM + K */
#define CH2_  128        /* scan chunks */
#define CL2_  32         /* rows per chunk = L_/CH2_ */
#define PSTR_ 1752       /* packed projection row: 780 Z | 768 Q | 12 G | 192 LAT */
#define QOFF_ 780
#define GOFF_ 1548
#define LOFF_ 1560
#define WPAD_ 1792       /* WallT col padding: 14 tiles x 128 */

__device__ __forceinline__ float softplusf(float x){ return log1pf(__expf(x)); }
__device__ __forceinline__ float sigmoidf(float x){ return 1.f / (1.f + __expf(-x)); }

// async global->LDS, 16B per lane; LDS dest is linear (base + lane*16)
#define GLOAD16(gp, lp) __builtin_amdgcn_global_load_lds( \
    (const __attribute__((address_space(1))) unsigned int*)(gp), \
    (__attribute__((address_space(3))) unsigned int*)(lp), 16, 0, 0)

// bijective XCD swizzle (8 XCDs): contiguous wg chunk per XCD
__device__ __forceinline__ int xcd_swz(int bid, int nwg)
{
    const int q = nwg >> 3, r = nwg & 7;
    const int x = bid & 7, y = bid >> 3;
    return (x < r ? x * (q + 1) : r * (q + 1) + (x - r) * q) + y;
}

// dtype probe: score_scale == ones; f32 1.0 -> 0x3F800000
__global__ void probe_k(const unsigned* __restrict__ ss, int* __restrict__ md)
{
    if (threadIdx.x == 0 && blockIdx.x == 0) {
        unsigned w = ss[0];
        int m = 0;
        if      (w == 0x3F803F80u) m = 1;
        else if (w == 0x3C003C00u) m = 2;
        else if (w == 0x00000000u) m = 3;
        else if (w != 0x3F800000u) m = 4;
        md[0] = m;
    }
}

__global__ void fillf_k(float* __restrict__ p, long n, float v)
{
    for (long i = (long)blockIdx.x * blockDim.x + threadIdx.x; i < n;
         i += (long)gridDim.x * blockDim.x) p[i] = v;
}
__global__ void guard_k(const int* __restrict__ md, float* __restrict__ p, long n)
{
    const int m = *md;
    if (m == 0) return;
    for (long i = (long)blockIdx.x * blockDim.x + threadIdx.x; i < n;
         i += (long)gridDim.x * blockDim.x) p[i] = 4000.f + m;
}

// ---------------------------------------------------------------------------
// f16 single-product MFMA GEMM (r4/r7-verified structure, BK=64).
// C[M,N] = A[M,Kd] @ B[Kd,N]; A [row][Kd] f16, B transposed [col][Kd] f16.
// Tile 128x128, 256 thr = 4 waves (2x2), 64x64/wave. LDS [128][64] f16 per
// operand; gload_lds staging with linear dest + inverse-XOR-swizzled source
// (q = l7 ^ (row&7)); fragment reads deswizzle -> conflict-free (r4-verified
// SQ_LDS_BANK_CONFLICT = 0). 1D grid nTn*nTm, XCD-swizzled.
// Optional fused LAT output: if Cl != nullptr, columns [LOFF_, LOFF_+192)
// are additionally stored as f16 to Cl[gm*192 + (gn-LOFF_)] (proj GEMM only).
// M mult of 128, Kd mult of 64.
// ---------------------------------------------------------------------------
__global__ __launch_bounds__(256, 4) void gemmh_k(
    const f16* __restrict__ Ag, const f16* __restrict__ Bg,
    float* __restrict__ C, f16* __restrict__ Cl,
    int N, int Kd, int lda, int ldb, int ldc, int nTn)
{
    __shared__ __align__(16) f16 As[128 * 64];
    __shared__ __align__(16) f16 Bs[128 * 64];

    const int wg = xcd_swz(blockIdx.x, gridDim.x);
    const int n0 = (wg % nTn) * 128, m0 = (wg / nTn) * 128;
    const int tid  = threadIdx.x;
    const int lane = tid & 63, wave = tid >> 6;
    const int wm = (wave >> 1) * 64, wn = (wave & 1) * 64;
    const int lr = lane & 15, lg = lane >> 4;
    const int l8 = lane >> 3, l7 = lane & 7;

    f32x4 acc[4][4];
    #pragma unroll
    for (int i = 0; i < 4; i++)
        #pragma unroll
        for (int j = 0; j < 4; j++) acc[i][j] = (f32x4){0.f, 0.f, 0.f, 0.f};

    for (int k0 = 0; k0 < Kd; k0 += 64) {
        #pragma unroll
        for (int i = 0; i < 4; i++) {           // A tile: 128 rows x 64 f16
            const int rl = i * 32 + wave * 8 + l8;
            const int q  = l7 ^ (rl & 7);
            GLOAD16(Ag + (long)(m0 + rl) * lda + k0 + q * 8,
                    &As[i * 2048 + wave * 512 + lane * 8]);
        }
        #pragma unroll
        for (int i = 0; i < 4; i++) {           // B tile
            const int rl = i * 32 + wave * 8 + l8;
            const int q  = l7 ^ (rl & 7);
            GLOAD16(Bg + (long)(n0 + rl) * ldb + k0 + q * 8,
                    &Bs[i * 2048 + wave * 512 + lane * 8]);
        }
        __syncthreads();

        f16x8 af[4][2], bf[4][2];
        #pragma unroll
        for (int f = 0; f < 4; f++) {
            #pragma unroll
            for (int kk = 0; kk < 2; kk++) {
                const int ra = wm + f * 16 + lr;
                const int ca = (kk * 4 + lg) ^ (ra & 7);
                af[f][kk] = *(const f16x8*)&As[ra * 64 + ca * 8];
                const int rb = wn + f * 16 + lr;
                const int cb = (kk * 4 + lg) ^ (rb & 7);
                bf[f][kk] = *(const f16x8*)&Bs[rb * 64 + cb * 8];
            }
        }
        #pragma unroll
        for (int i = 0; i < 4; i++)
            #pragma unroll
            for (int j = 0; j < 4; j++) {
                acc[i][j] = __builtin_amdgcn_mfma_f32_16x16x32_f16(af[i][0], bf[j][0], acc[i][j], 0, 0, 0);
                acc[i][j] = __builtin_amdgcn_mfma_f32_16x16x32_f16(af[i][1], bf[j][1], acc[i][j], 0, 0, 0);
            }
        __syncthreads();
    }

    // D layout: col = lane&15, row = (lane>>4)*4 + reg
    #pragma unroll
    for (int i = 0; i < 4; i++) {
        #pragma unroll
        for (int j = 0; j < 4; j++) {
            const int gn = n0 + wn + j * 16 + lr;
            if (gn < N) {
                #pragma unroll
                for (int r = 0; r < 4; r++) {
                    const int gm = m0 + wm + i * 16 + lg * 4 + r;
                    const float v = acc[i][j][r];
                    C[(long)gm * ldc + gn] = v;
                    if (Cl != nullptr && gn >= LOFF_)   // gn < LOFF_+192 == N
                        Cl[(long)gm * 192 + (gn - LOFF_)] = (f16)v;
                }
            }
        }
    }
}

// ---------------------------------------------------------------------------
// Fused stage 3+4 (f16 single-product) — unchanged from r7 except occupancy.
// ---------------------------------------------------------------------------
__global__ __launch_bounds__(256, 4) void stage34h_k(
    const f16* __restrict__ OUTAh, const f16* __restrict__ LATh,
    const f16* __restrict__ WriT, const f16* __restrict__ WupT,
    f16* __restrict__ yah)
{
    __shared__ __align__(16) f16 As[128 * 64];
    __shared__ __align__(16) f16 Bs[128 * 64];

    const int wg = xcd_swz(blockIdx.x, gridDim.x);
    const int n0 = (wg % 36) * 128, m0 = (wg / 36) * 128;
    const int k  = n0 / 384;
    const int tid  = threadIdx.x;
    const int lane = tid & 63, wave = tid >> 6;
    const int wm = (wave >> 1) * 64, wn = (wave & 1) * 64;
    const int lr = lane & 15, lg = lane >> 4;
    const int l8 = lane >> 3, l7 = lane & 7;

    f32x4 acc[4][4];
    #pragma unroll
    for (int i = 0; i < 4; i++)
        #pragma unroll
        for (int j = 0; j < 4; j++) acc[i][j] = (f32x4){0.f, 0.f, 0.f, 0.f};

    #pragma unroll
    for (int ph = 0; ph < 2; ph++) {
        const int Kd  = ph ? 192 : 128;
        const f16* Ab = ph ? LATh : OUTAh + k * 128;
        const int lda = ph ? 192 : 1536;
        const f16* Bb = ph ? WupT + (long)n0 * 192 : WriT + (long)(k * 384) * 128 + (long)(n0 - k * 384) * 128;
        const int ldb = ph ? 192 : 128;

        for (int k0 = 0; k0 < Kd; k0 += 64) {
            #pragma unroll
            for (int i = 0; i < 4; i++) {
                const int rl = i * 32 + wave * 8 + l8;
                const int q  = l7 ^ (rl & 7);
                GLOAD16(Ab + (long)(m0 + rl) * lda + k0 + q * 8,
                        &As[i * 2048 + wave * 512 + lane * 8]);
            }
            #pragma unroll
            for (int i = 0; i < 4; i++) {
                const int rl = i * 32 + wave * 8 + l8;
                const int q  = l7 ^ (rl & 7);
                GLOAD16(Bb + (long)rl * ldb + k0 + q * 8,
                        &Bs[i * 2048 + wave * 512 + lane * 8]);
            }
            __syncthreads();

            f16x8 af[4][2], bf[4][2];
            #pragma unroll
            for (int f = 0; f < 4; f++) {
                #pragma unroll
                for (int kk = 0; kk < 2; kk++) {
                    const int ra = wm + f * 16 + lr;
                    const int ca = (kk * 4 + lg) ^ (ra & 7);
                    af[f][kk] = *(const f16x8*)&As[ra * 64 + ca * 8];
                    const int rb = wn + f * 16 + lr;
                    const int cb = (kk * 4 + lg) ^ (rb & 7);
                    bf[f][kk] = *(const f16x8*)&Bs[rb * 64 + cb * 8];
                }
            }
            #pragma unroll
            for (int i = 0; i < 4; i++)
                #pragma unroll
                for (int j = 0; j < 4; j++) {
                    acc[i][j] = __builtin_amdgcn_mfma_f32_16x16x32_f16(af[i][0], bf[j][0], acc[i][j], 0, 0, 0);
                    acc[i][j] = __builtin_amdgcn_mfma_f32_16x16x32_f16(af[i][1], bf[j][1], acc[i][j], 0, 0, 0);
                }
            __syncthreads();
        }
    }

    // epilogue: (yv,yg) interleaved in adjacent cols -> adjacent lanes
    #pragma unroll
    for (int i = 0; i < 4; i++) {
        #pragma unroll
        for (int j = 0; j < 4; j++) {
            const int gc  = n0 + wn + j * 16 + lr;
            const int yac = k * 192 + ((gc - k * 384) >> 1);
            #pragma unroll
            for (int r = 0; r < 4; r++) {
                const int gm = m0 + wm + i * 16 + lg * 4 + r;
                const float v = acc[i][j][r];
                const float p = __shfl_xor(v, 1);
                if (!(lane & 1)) {
                    const float g = p;
                    yah[(long)gm * 2304 + yac] = (f16)(v * g * sigmoidf(g));
                }
            }
        }
    }
}

// ---------------------------------------------------------------------------
// Pack kernels — LDS 64x65 tile-transpose: coalesced reads AND writes.
// ---------------------------------------------------------------------------
__global__ void packxh_k(const float* __restrict__ x, f16* __restrict__ xh, long n)
{
    for (long t = (long)blockIdx.x * blockDim.x + threadIdx.x; t < n;
         t += (long)gridDim.x * blockDim.x) xh[t] = (f16)x[t];
}

// WallT[c][r] (c<1792, r<768) from piecewise [W_mem | W_q | Wg | W_dn].
// grid (12 r-tiles, 28 c-tiles), 256 thr.
__global__ void packwallT_k(const float* __restrict__ Wm, const float* __restrict__ Wq,
                            const float* __restrict__ Wg_, const float* __restrict__ Wd,
                            f16* __restrict__ WT)
{
    __shared__ float T[64][65];
    const int rb = blockIdx.x * 64, cb = blockIdx.y * 64;
    const int lc = threadIdx.x & 63, lw = threadIdx.x >> 6;
    #pragma unroll
    for (int w = 0; w < 16; w++) {
        const int r = rb + lw + w * 4, c = cb + lc;
        float v = 0.f;
        if      (c < QOFF_) v = Wm[(long)r * ZC_ + c];
        else if (c < GOFF_) v = Wq[(long)r * 768 + (c - QOFF_)];
        else if (c < LOFF_) v = Wg_[(long)r * 12 + (c - GOFF_)];
        else if (c < PSTR_) v = Wd[(long)r * 192 + (c - LOFF_)];
        T[lw + w * 4][lc] = v;
    }
    __syncthreads();
    #pragma unroll
    for (int w = 0; w < 16; w++) {
        const int c = lw + w * 4;
        WT[(long)(cb + c) * 768 + rb + lc] = (f16)T[lc][c];
    }
}

// WriT[(k*384+cp)][rr] (cp interleaved, rr<128): transpose per (k, j-tile).
// grid (6 j-tiles, 12 k), 256 thr. j-tiles never straddle the 192 boundary.
__global__ void packriT_k(const float* __restrict__ Wre, const float* __restrict__ Wim,
                          f16* __restrict__ WT)
{
    __shared__ float T[64][130];
    const int jb = blockIdx.x * 64, k = blockIdx.y;
    const int lc = threadIdx.x & 63, lw = threadIdx.x >> 6;
    #pragma unroll
    for (int w = 0; w < 32; w++) {
        const int rr = lw + w * 4;
        const float* S = (rr < 64) ? Wre + ((long)k * 64 + rr) * 384
                                   : Wim + ((long)k * 64 + rr - 64) * 384;
        T[lc][rr] = S[jb + lc];
    }
    __syncthreads();
    const int rl = threadIdx.x & 127, jh = threadIdx.x >> 7;
    #pragma unroll
    for (int w = 0; w < 32; w++) {
        const int jl = jh + w * 2;
        const int j  = jb + jl;
        const int cp = (j < 192) ? 2 * j : 2 * (j - 192) + 1;
        WT[((long)k * 384 + cp) * 128 + rl] = (f16)T[jl][rl];
    }
}

// WupT[(k*384+cp)][r] (r<192), highway folded. grid (6 j-tiles, 3 r-tiles, 12 k).
__global__ void packupT_k(const float* __restrict__ Wup, const float* __restrict__ hw,
                          f16* __restrict__ WT)
{
    __shared__ float T[64][65];
    const int jb = blockIdx.x * 64, rb = blockIdx.y * 64, k = blockIdx.z;
    const float hwk = hw[k];
    const int lc = threadIdx.x & 63, lw = threadIdx.x >> 6;
    #pragma unroll
    for (int w = 0; w < 16; w++) {
        const int r = rb + lw + w * 4;
        T[lw + w * 4][lc] = Wup[(long)r * 4608 + k * 384 + jb + lc] * hwk;
    }
    __syncthreads();
    #pragma unroll
    for (int w = 0; w < 16; w++) {
        const int jl = lw + w * 4;
        const int j  = jb + jl;
        const int cp = (j < 192) ? 2 * j : 2 * (j - 192) + 1;
        WT[((long)k * 384 + cp) * 192 + rb + lc] = (f16)T[lc][jl];
    }
}

// WoutT[c][r] (c<768, r<2304) from W_out[2304][768]. grid (36 r-tiles, 12 c-tiles).
__global__ void packoutT_k(const float* __restrict__ Wout, f16* __restrict__ WT)
{
    __shared__ float T[64][65];
    const int rb = blockIdx.x * 64, cb = blockIdx.y * 64;
    const int lc = threadIdx.x & 63, lw = threadIdx.x >> 6;
    #pragma unroll
    for (int w = 0; w < 16; w++) {
        const int r = lw + w * 4;
        T[r][lc] = Wout[(long)(rb + r) * 768 + (cb + lc)];
    }
    __syncthreads();
    #pragma unroll
    for (int w = 0; w < 16; w++) {
        const int c = lw + w * 4;
        WT[(long)(cb + c) * 2304 + rb + lc] = (f16)T[lc][c];
    }
}

// ---------------------------------------------------------------------------
// Fused scan (unchanged from r7): batch via blockIdx.z, emits OUTAh f16.
// ---------------------------------------------------------------------------
template<bool FINAL>
__global__ __launch_bounds__(64) void scan_k(
    const float* __restrict__ Pb, const float* __restrict__ convk,
    const float* __restrict__ theta, const float* __restrict__ decay,
    const float* __restrict__ ssc, const float* __restrict__ nsc,
    const float* __restrict__ bg, float* __restrict__ csumb,
    f16* __restrict__ OUTAhb)
{
    const int zb = blockIdx.z;
    const float* P  = Pb + (long)zb * L_ * PSTR_;
    float* csum     = csumb + (long)zb * K_ * CH2_ * 129;
    f16* OUTAh      = FINAL ? OUTAhb + (long)zb * L_ * 1536 : nullptr;

    const int ch = blockIdx.x, k = blockIdx.y, h = threadIdx.x;
    const int col = k * 64 + h, scol = 768 + k;
    const int l0 = ch * CL2_;

    const float ck0 = convk[col],  ck1 = convk[ZC_ + col];
    const float ck2 = convk[2 * ZC_ + col], ck3 = convk[3 * ZC_ + col];
    const float cs0 = convk[scol], cs1 = convk[ZC_ + scol];
    const float cs2 = convk[2 * ZC_ + scol], cs3 = convk[3 * ZC_ + scol];

    const float th    = softplusf(theta[k * 64 + h]) + 0.001f;
    const float slope = softplusf(decay[k]);
    const float sscal = ssc[k];
    const float ns    = FINAL ? nsc[k * 64 + h] : 0.f;
    const float bgk   = FINAL ? bg[k] : 0.f;
    const int   kq    = k >> 1;

    const long cb = ((long)k * CH2_ + ch) * 129;
    float dacc = 0.f, racc = 0.f, iacc = 0.f;
    if (FINAL) { dacc = csum[cb]; racc = csum[cb + 1 + h]; iacc = csum[cb + 65 + h]; }

    for (int p = 0; p < CL2_; p++) {
        const int l = l0 + p;
        float kv, sr;
        if (l >= 3) {
            const float* zb2 = P + (long)(l - 3) * PSTR_;
            kv = ck0 * zb2[col]  + ck1 * zb2[PSTR_ + col]
               + ck2 * zb2[2 * PSTR_ + col] + ck3 * zb2[3 * PSTR_ + col];
            sr = cs0 * zb2[scol] + cs1 * zb2[PSTR_ + scol]
               + cs2 * zb2[2 * PSTR_ + scol] + cs3 * zb2[3 * PSTR_ + scol];
        } else {
            kv = ck3 * P[(long)l * PSTR_ + col];
            sr = cs3 * P[(long)l * PSTR_ + scol];
            if (l >= 1) { kv += ck2 * P[(long)(l - 1) * PSTR_ + col];
                          sr += cs2 * P[(long)(l - 1) * PSTR_ + scol]; }
            if (l >= 2) { kv += ck1 * P[(long)(l - 2) * PSTR_ + col];
                          sr += cs1 * P[(long)(l - 2) * PSTR_ + scol]; }
        }
        const float lp = fminf(fmaxf(sscal * sr, -20.f), 20.f);
        const float pw = __expf(lp - slope * (float)(L_ - 1 - l));
        const float phi = tanhf(kv) * th;
        float sn, cn; __sincosf(phi, &sn, &cn);
        dacc += pw; racc += kv * pw * cn; iacc += kv * pw * sn;

        if (FINAL) {
            const float invd = 1.f / fmaxf(dacc, 1e-4f);
            const float sre = racc * invd, sim = iacc * invd;
            const float qr = P[(long)l * PSTR_ + QOFF_ + (kq * 64 + h) * 2];
            const float qi = P[(long)l * PSTR_ + QOFF_ + (kq * 64 + h) * 2 + 1];
            const float gate = sigmoidf(P[(long)l * PSTR_ + GOFF_ + k] + bgk);
            const float s2 = ns * gate;
            f16* orow = OUTAh + (long)l * 1536 + k * 128;
            orow[h]      = (f16)((sre * qr + sim * qi) * s2);
            orow[64 + h] = (f16)((sim * qr - sre * qi) * s2);
        }
    }
    if (!FINAL) {
        if (h == 0) csum[cb] = dacc;
        csum[cb + 1 + h]  = racc;
        csum[cb + 65 + h] = iacc;
    }
}

// exclusive prefix over the 128 chunks, per (batch=blockIdx.y, k, entry).
__global__ void scan2_k(float* __restrict__ csumb)
{
    float* csum = csumb + (long)blockIdx.y * K_ * CH2_ * 129;
    const int k = blockIdx.x;
    const int t = threadIdx.x;
    if (t >= 129) return;
    float run = 0.f;
    for (int g = 0; g < CH2_; g += 32) {
        float v[32];
        #pragma unroll
        for (int c = 0; c < 32; c++)
            v[c] = csum[((long)k * CH2_ + g + c) * 129 + t];
        #pragma unroll
        for (int c = 0; c < 32; c++) { const float x = v[c]; v[c] = run; run += x; }
        #pragma unroll
        for (int c = 0; c < 32; c++)
            csum[((long)k * CH2_ + g + c) * 129 + t] = v[c];
    }
}

// ---------------------------------------------------------------------------
extern "C" void kernel_launch(void* const* d_in, const int* in_sizes, int n_in,
                              void* d_out, int out_size, void* d_ws, size_t ws_size,
                              hipStream_t stream)
{
    float* out = (float*)d_out;   // f32 output (verified r8)
    const dim3 blk(256);

    // tripwire: input ordering/sizes
    const int expSz[16] = {12582912, 599040, 3120, 589824, 768, 12, 12,
                           294912, 294912, 768, 9216, 12, 147456, 884736,
                           12, 1769472};
    int bad = -1;
    if (n_in != 16) bad = 99;
    else { for (int i = 0; i < 16; i++) if (in_sizes[i] != expSz[i]) { bad = i; break; } }
    if (out_size != 12582912 && bad < 0) bad = 98;
    if (bad >= 0) {
        fillf_k<<<dim3(2048), blk, 0, stream>>>(out, out_size, 3000.f + bad);
        return;
    }

    const float* x     = (const float*)d_in[0];
    const float* W_mem = (const float*)d_in[1];
    const float* convk = (const float*)d_in[2];
    const float* W_q   = (const float*)d_in[3];
    const float* theta = (const float*)d_in[4];
    const float* decay = (const float*)d_in[5];
    const float* ssc   = (const float*)d_in[6];
    const float* W_re  = (const float*)d_in[7];
    const float* W_im  = (const float*)d_in[8];
    const float* nsc   = (const float*)d_in[9];
    const float* Wg    = (const float*)d_in[10];
    const float* bg    = (const float*)d_in[11];
    const float* W_dn  = (const float*)d_in[12];
    const float* W_up  = (const float*)d_in[13];
    const float* hw    = (const float*)d_in[14];
    const float* W_out = (const float*)d_in[15];

    // ---- workspace ladder: cfg0 full-batch; cfg1 per-batch acts + full yah;
    //      cfg2 everything per-batch.
    size_t o[12];
    auto plan = [&](bool fullP, bool fullY, size_t* oo) -> size_t {
        const long rp = fullP ? (long)B_ * L_ : L_;
        const long ry = fullY ? (long)B_ * L_ : L_;
        size_t off = 0;
        auto al = [&](size_t bytes) {
            size_t cur = off; off = (off + bytes + 255) & ~(size_t)255; return cur;
        };
        oo[0]  = al(4);                                   // md
        oo[1]  = al((size_t)B_ * K_ * CH2_ * 129 * 4);    // csum (all batches)
        oo[2]  = al((size_t)rp * 768 * 2);                // xh (f16)
        oo[3]  = al((size_t)rp * PSTR_ * 4);              // Pall (f32)
        oo[4]  = al((size_t)rp * 1536 * 2);               // OUTAh (f16)
        oo[5]  = al((size_t)rp * 192 * 2);                // LATh (f16)
        oo[6]  = al((size_t)ry * 2304 * 2);               // yah (f16)
        oo[7]  = al((size_t)WPAD_ * 768 * 2);             // WallT
        oo[8]  = al((size_t)K_ * 384 * 128 * 2);          // WriT
        oo[9]  = al((size_t)4608 * 192 * 2);              // WupT
        oo[10] = al((size_t)768 * 2304 * 2);              // WoutT
        return off;
    };
    const int nCfg = 3;
    const bool cfgP[nCfg] = {true, false, false};
    const bool cfgY[nCfg] = {true, true,  false};
    int cfg = -1;
    for (int c = 0; c < nCfg; c++) {
        size_t t = plan(cfgP[c], cfgY[c], o);
        if (t + 4096 <= ws_size) { cfg = c; break; }
    }
    if (cfg < 0) {
        fillf_k<<<dim3(2048), blk, 0, stream>>>(out, (long)out_size, 1000.f);
        return;
    }
    const bool FULLP = cfgP[cfg], FULLY = cfgY[cfg];

    char* ws = (char*)d_ws;
    int*   md    = (int*)(ws + o[0]);
    float* csum  = (float*)(ws + o[1]);
    f16*   xh    = (f16*)(ws + o[2]);
    float* Pall  = (float*)(ws + o[3]);
    f16*   OUTAh = (f16*)(ws + o[4]);
    f16*   LATh  = (f16*)(ws + o[5]);
    f16*   yah   = (f16*)(ws + o[6]);
    f16*   WallT = (f16*)(ws + o[7]);
    f16*   WriT  = (f16*)(ws + o[8]);
    f16*   WupT  = (f16*)(ws + o[9]);
    f16*   WoutT = (f16*)(ws + o[10]);

    probe_k<<<dim3(1), dim3(64), 0, stream>>>((const unsigned*)ssc, md);
    packwallT_k<<<dim3(12, 28), blk, 0, stream>>>(W_mem, W_q, Wg, W_dn, WallT);
    packriT_k<<<dim3(6, 12), blk, 0, stream>>>(W_re, W_im, WriT);
    packupT_k<<<dim3(6, 3, 12), blk, 0, stream>>>(W_up, hw, WupT);
    packoutT_k<<<dim3(36, 12), blk, 0, stream>>>(W_out, WoutT);

    const int nb    = FULLP ? 1 : B_;
    const long Mr   = FULLP ? (long)B_ * L_ : L_;
    const int nTm   = (int)(Mr / 128);
    const int zGrid = FULLP ? B_ : 1;

    for (int b = 0; b < nb; b++) {
        const float* xb = x + (long)b * L_ * 768;

        // pack x -> f16, then merged projection GEMM: Pall = x @ Wall
        // (LAT f16 plane emitted directly by the GEMM epilogue)
        packxh_k<<<dim3(4096), blk, 0, stream>>>(xb, xh, Mr * 768);
        gemmh_k<<<dim3(14 * nTm), blk, 0, stream>>>(
            xh, WallT, Pall, LATh, 1752, 768, 768, 768, 1752, 14);

        // fused chunked scan, 3 passes -> OUTAh (f16)
        scan_k<false><<<dim3(CH2_, K_, zGrid), dim3(64), 0, stream>>>(
            Pall, convk, theta, decay, ssc, nsc, bg, csum, nullptr);
        scan2_k<<<dim3(K_, zGrid), dim3(192), 0, stream>>>(csum);
        scan_k<true><<<dim3(CH2_, K_, zGrid), dim3(64), 0, stream>>>(
            Pall, convk, theta, decay, ssc, nsc, bg, csum, OUTAh);

        // fused stage 3+4 -> ya (f16)
        f16* yd = (FULLY && !FULLP) ? yah + (long)b * L_ * 2304 : yah;
        stage34h_k<<<dim3(36 * nTm), blk, 0, stream>>>(
            OUTAh, LATh, WriT, WupT, yd);

        if (!FULLY) {
            gemmh_k<<<dim3(6 * nTm), blk, 0, stream>>>(
                yah, WoutT, out + (long)b * L_ * 768, (f16*)nullptr,
                768, 2304, 2304, 2304, 768, 6);
        }
    }

    if (FULLY) {
        // one out-GEMM over all batches: (B*L) x 768, Kd=2304
        gemmh_k<<<dim3(6 * (int)((long)B_ * L_ / 128)), blk, 0, stream>>>(
            yah, WoutT, out, (f16*)nullptr, 768, 2304, 2304, 2304, 768, 6);
    }

    guard_k<<<dim3(2048), blk, 0, stream>>>(md, out, (long)out_size);
}

// Round 9
// 448.147 us; speedup vs baseline: 1.4555x; 1.4555x over previous
//
#include <hip/hip_runtime.h>

typedef __attribute__((ext_vector_type(8))) _Float16 f16x8;
typedef __attribute__((ext_vector_type(4))) float f32x4;
typedef _Float16 f16;

#define B_    4
#define L_    4096
#define K_    12
#define ZC_   780        /* MEM + K */
#define CH2_  128        /* scan chunks */
#define CL2_  32         /* rows per chunk = L_/CH2_ */
#define PSTR_ 1752       /* proj GEMM N: 780 Z | 768 Q | 12 G | 192 LAT */
#define QOFF_ 780
#define GOFF_ 1548
#define LOFF_ 1560
#define PS2_  800        /* Pall row: 780 Z | 12 G | 8 pad (f32) */
#define WPAD_ 1792       /* WallT col padding: 14 tiles x 128 */

__device__ __forceinline__ float softplusf(float x){ return log1pf(__expf(x)); }
__device__ __forceinline__ float sigmoidf(float x){ return 1.f / (1.f + __expf(-x)); }

// async global->LDS, 16B per lane; LDS dest is linear (base + lane*16)
#define GLOAD16(gp, lp) __builtin_amdgcn_global_load_lds( \
    (const __attribute__((address_space(1))) unsigned int*)(gp), \
    (__attribute__((address_space(3))) unsigned int*)(lp), 16, 0, 0)

// bijective XCD swizzle (8 XCDs): contiguous wg chunk per XCD
__device__ __forceinline__ int xcd_swz(int bid, int nwg)
{
    const int q = nwg >> 3, r = nwg & 7;
    const int x = bid & 7, y = bid >> 3;
    return (x < r ? x * (q + 1) : r * (q + 1) + (x - r) * q) + y;
}

// dtype probe: score_scale == ones; f32 1.0 -> 0x3F800000
__global__ void probe_k(const unsigned* __restrict__ ss, int* __restrict__ md)
{
    if (threadIdx.x == 0 && blockIdx.x == 0) {
        unsigned w = ss[0];
        int m = 0;
        if      (w == 0x3F803F80u) m = 1;
        else if (w == 0x3C003C00u) m = 2;
        else if (w == 0x00000000u) m = 3;
        else if (w != 0x3F800000u) m = 4;
        md[0] = m;
    }
}

__global__ void fillf_k(float* __restrict__ p, long n, float v)
{
    for (long i = (long)blockIdx.x * blockDim.x + threadIdx.x; i < n;
         i += (long)gridDim.x * blockDim.x) p[i] = v;
}
__global__ void guard_k(const int* __restrict__ md, float* __restrict__ p, long n)
{
    const int m = *md;
    if (m == 0) return;
    for (long i = (long)blockIdx.x * blockDim.x + threadIdx.x; i < n;
         i += (long)gridDim.x * blockDim.x) p[i] = 4000.f + m;
}

// ---------------------------------------------------------------------------
// f16 single-product MFMA GEMM (r4/r7-verified structure, BK=64).
// C[M,N] = A[M,Kd] @ B[Kd,N]; A [row][Kd] f16, B transposed [col][Kd] f16.
// Tile 128x128, 256 thr = 4 waves (2x2), 64x64/wave. LDS [128][64] f16 per
// operand; gload_lds staging, linear dest + inverse-XOR-swizzled source
// (q = l7 ^ (row&7)); fragment reads deswizzle -> conflict-free (r4-verified
// SQ_LDS_BANK_CONFLICT = 0). 1D grid nTn*nTm, XCD-swizzled.
// Proj mode (Qh != nullptr): epilogue routes by column —
//   gn<780 -> C f32 (ldc=PS2_), 780..1547 -> Qh f16, 1548..1559 -> C f32
//   at col 780+(gn-1548), 1560..1751 -> Cl (LATh) f16.
// Out mode (Qh == nullptr): plain f32 C store (stride ldc).
// M mult of 128, Kd mult of 64.
// ---------------------------------------------------------------------------
__global__ __launch_bounds__(256, 4) void gemmh_k(
    const f16* __restrict__ Ag, const f16* __restrict__ Bg,
    float* __restrict__ C, f16* __restrict__ Cl, f16* __restrict__ Qh,
    int N, int Kd, int lda, int ldb, int ldc, int nTn)
{
    __shared__ __align__(16) f16 As[128 * 64];
    __shared__ __align__(16) f16 Bs[128 * 64];

    const int wg = xcd_swz(blockIdx.x, gridDim.x);
    const int n0 = (wg % nTn) * 128, m0 = (wg / nTn) * 128;
    const int tid  = threadIdx.x;
    const int lane = tid & 63, wave = tid >> 6;
    const int wm = (wave >> 1) * 64, wn = (wave & 1) * 64;
    const int lr = lane & 15, lg = lane >> 4;
    const int l8 = lane >> 3, l7 = lane & 7;

    f32x4 acc[4][4];
    #pragma unroll
    for (int i = 0; i < 4; i++)
        #pragma unroll
        for (int j = 0; j < 4; j++) acc[i][j] = (f32x4){0.f, 0.f, 0.f, 0.f};

    for (int k0 = 0; k0 < Kd; k0 += 64) {
        #pragma unroll
        for (int i = 0; i < 4; i++) {           // A tile: 128 rows x 64 f16
            const int rl = i * 32 + wave * 8 + l8;
            const int q  = l7 ^ (rl & 7);
            GLOAD16(Ag + (long)(m0 + rl) * lda + k0 + q * 8,
                    &As[i * 2048 + wave * 512 + lane * 8]);
        }
        #pragma unroll
        for (int i = 0; i < 4; i++) {           // B tile
            const int rl = i * 32 + wave * 8 + l8;
            const int q  = l7 ^ (rl & 7);
            GLOAD16(Bg + (long)(n0 + rl) * ldb + k0 + q * 8,
                    &Bs[i * 2048 + wave * 512 + lane * 8]);
        }
        __syncthreads();

        f16x8 af[4][2], bf[4][2];
        #pragma unroll
        for (int f = 0; f < 4; f++) {
            #pragma unroll
            for (int kk = 0; kk < 2; kk++) {
                const int ra = wm + f * 16 + lr;
                const int ca = (kk * 4 + lg) ^ (ra & 7);
                af[f][kk] = *(const f16x8*)&As[ra * 64 + ca * 8];
                const int rb = wn + f * 16 + lr;
                const int cb = (kk * 4 + lg) ^ (rb & 7);
                bf[f][kk] = *(const f16x8*)&Bs[rb * 64 + cb * 8];
            }
        }
        #pragma unroll
        for (int i = 0; i < 4; i++)
            #pragma unroll
            for (int j = 0; j < 4; j++) {
                acc[i][j] = __builtin_amdgcn_mfma_f32_16x16x32_f16(af[i][0], bf[j][0], acc[i][j], 0, 0, 0);
                acc[i][j] = __builtin_amdgcn_mfma_f32_16x16x32_f16(af[i][1], bf[j][1], acc[i][j], 0, 0, 0);
            }
        __syncthreads();
    }

    // D layout: col = lane&15, row = (lane>>4)*4 + reg
    #pragma unroll
    for (int i = 0; i < 4; i++) {
        #pragma unroll
        for (int j = 0; j < 4; j++) {
            const int gn = n0 + wn + j * 16 + lr;
            if (gn < N) {
                #pragma unroll
                for (int r = 0; r < 4; r++) {
                    const int gm = m0 + wm + i * 16 + lg * 4 + r;
                    const float v = acc[i][j][r];
                    if (Qh != nullptr) {        // proj routing
                        if      (gn < QOFF_) C[(long)gm * ldc + gn] = v;
                        else if (gn < GOFF_) Qh[(long)gm * 768 + (gn - QOFF_)] = (f16)v;
                        else if (gn < LOFF_) C[(long)gm * ldc + QOFF_ + (gn - GOFF_)] = v;
                        else                 Cl[(long)gm * 192 + (gn - LOFF_)] = (f16)v;
                    } else {
                        C[(long)gm * ldc + gn] = v;
                    }
                }
            }
        }
    }
}

// ---------------------------------------------------------------------------
// Fused stage 3+4 (f16 single-product) — unchanged from r8.
// ---------------------------------------------------------------------------
__global__ __launch_bounds__(256, 4) void stage34h_k(
    const f16* __restrict__ OUTAh, const f16* __restrict__ LATh,
    const f16* __restrict__ WriT, const f16* __restrict__ WupT,
    f16* __restrict__ yah)
{
    __shared__ __align__(16) f16 As[128 * 64];
    __shared__ __align__(16) f16 Bs[128 * 64];

    const int wg = xcd_swz(blockIdx.x, gridDim.x);
    const int n0 = (wg % 36) * 128, m0 = (wg / 36) * 128;
    const int k  = n0 / 384;
    const int tid  = threadIdx.x;
    const int lane = tid & 63, wave = tid >> 6;
    const int wm = (wave >> 1) * 64, wn = (wave & 1) * 64;
    const int lr = lane & 15, lg = lane >> 4;
    const int l8 = lane >> 3, l7 = lane & 7;

    f32x4 acc[4][4];
    #pragma unroll
    for (int i = 0; i < 4; i++)
        #pragma unroll
        for (int j = 0; j < 4; j++) acc[i][j] = (f32x4){0.f, 0.f, 0.f, 0.f};

    #pragma unroll
    for (int ph = 0; ph < 2; ph++) {
        const int Kd  = ph ? 192 : 128;
        const f16* Ab = ph ? LATh : OUTAh + k * 128;
        const int lda = ph ? 192 : 1536;
        const f16* Bb = ph ? WupT + (long)n0 * 192 : WriT + (long)(k * 384) * 128 + (long)(n0 - k * 384) * 128;
        const int ldb = ph ? 192 : 128;

        for (int k0 = 0; k0 < Kd; k0 += 64) {
            #pragma unroll
            for (int i = 0; i < 4; i++) {
                const int rl = i * 32 + wave * 8 + l8;
                const int q  = l7 ^ (rl & 7);
                GLOAD16(Ab + (long)(m0 + rl) * lda + k0 + q * 8,
                        &As[i * 2048 + wave * 512 + lane * 8]);
            }
            #pragma unroll
            for (int i = 0; i < 4; i++) {
                const int rl = i * 32 + wave * 8 + l8;
                const int q  = l7 ^ (rl & 7);
                GLOAD16(Bb + (long)rl * ldb + k0 + q * 8,
                        &Bs[i * 2048 + wave * 512 + lane * 8]);
            }
            __syncthreads();

            f16x8 af[4][2], bf[4][2];
            #pragma unroll
            for (int f = 0; f < 4; f++) {
                #pragma unroll
                for (int kk = 0; kk < 2; kk++) {
                    const int ra = wm + f * 16 + lr;
                    const int ca = (kk * 4 + lg) ^ (ra & 7);
                    af[f][kk] = *(const f16x8*)&As[ra * 64 + ca * 8];
                    const int rb = wn + f * 16 + lr;
                    const int cb = (kk * 4 + lg) ^ (rb & 7);
                    bf[f][kk] = *(const f16x8*)&Bs[rb * 64 + cb * 8];
                }
            }
            #pragma unroll
            for (int i = 0; i < 4; i++)
                #pragma unroll
                for (int j = 0; j < 4; j++) {
                    acc[i][j] = __builtin_amdgcn_mfma_f32_16x16x32_f16(af[i][0], bf[j][0], acc[i][j], 0, 0, 0);
                    acc[i][j] = __builtin_amdgcn_mfma_f32_16x16x32_f16(af[i][1], bf[j][1], acc[i][j], 0, 0, 0);
                }
            __syncthreads();
        }
    }

    // epilogue: (yv,yg) interleaved in adjacent cols -> adjacent lanes
    #pragma unroll
    for (int i = 0; i < 4; i++) {
        #pragma unroll
        for (int j = 0; j < 4; j++) {
            const int gc  = n0 + wn + j * 16 + lr;
            const int yac = k * 192 + ((gc - k * 384) >> 1);
            #pragma unroll
            for (int r = 0; r < 4; r++) {
                const int gm = m0 + wm + i * 16 + lg * 4 + r;
                const float v = acc[i][j][r];
                const float p = __shfl_xor(v, 1);
                if (!(lane & 1)) {
                    const float g = p;
                    yah[(long)gm * 2304 + yac] = (f16)(v * g * sigmoidf(g));
                }
            }
        }
    }
}

// ---------------------------------------------------------------------------
// Pack kernels — LDS 64x65 tile-transpose (r8-verified) + vectorized packxh.
// ---------------------------------------------------------------------------
__global__ void packxh_k(const float* __restrict__ x, f16* __restrict__ xh, long n8)
{
    const float4* x4 = (const float4*)x;
    for (long t = (long)blockIdx.x * blockDim.x + threadIdx.x; t < n8;
         t += (long)gridDim.x * blockDim.x) {
        const float4 a = x4[2 * t], b = x4[2 * t + 1];
        f16x8 o;
        o[0] = (f16)a.x; o[1] = (f16)a.y; o[2] = (f16)a.z; o[3] = (f16)a.w;
        o[4] = (f16)b.x; o[5] = (f16)b.y; o[6] = (f16)b.z; o[7] = (f16)b.w;
        *(f16x8*)(xh + t * 8) = o;
    }
}

// WallT[c][r] (c<1792, r<768) from piecewise [W_mem | W_q | Wg | W_dn].
__global__ void packwallT_k(const float* __restrict__ Wm, const float* __restrict__ Wq,
                            const float* __restrict__ Wg_, const float* __restrict__ Wd,
                            f16* __restrict__ WT)
{
    __shared__ float T[64][65];
    const int rb = blockIdx.x * 64, cb = blockIdx.y * 64;
    const int lc = threadIdx.x & 63, lw = threadIdx.x >> 6;
    #pragma unroll
    for (int w = 0; w < 16; w++) {
        const int r = rb + lw + w * 4, c = cb + lc;
        float v = 0.f;
        if      (c < QOFF_) v = Wm[(long)r * ZC_ + c];
        else if (c < GOFF_) v = Wq[(long)r * 768 + (c - QOFF_)];
        else if (c < LOFF_) v = Wg_[(long)r * 12 + (c - GOFF_)];
        else if (c < PSTR_) v = Wd[(long)r * 192 + (c - LOFF_)];
        T[lw + w * 4][lc] = v;
    }
    __syncthreads();
    #pragma unroll
    for (int w = 0; w < 16; w++) {
        const int c = lw + w * 4;
        WT[(long)(cb + c) * 768 + rb + lc] = (f16)T[lc][c];
    }
}

// WriT[(k*384+cp)][rr] (cp interleaved, rr<128): transpose per (k, j-tile).
__global__ void packriT_k(const float* __restrict__ Wre, const float* __restrict__ Wim,
                          f16* __restrict__ WT)
{
    __shared__ float T[64][130];
    const int jb = blockIdx.x * 64, k = blockIdx.y;
    const int lc = threadIdx.x & 63, lw = threadIdx.x >> 6;
    #pragma unroll
    for (int w = 0; w < 32; w++) {
        const int rr = lw + w * 4;
        const float* S = (rr < 64) ? Wre + ((long)k * 64 + rr) * 384
                                   : Wim + ((long)k * 64 + rr - 64) * 384;
        T[lc][rr] = S[jb + lc];
    }
    __syncthreads();
    const int rl = threadIdx.x & 127, jh = threadIdx.x >> 7;
    #pragma unroll
    for (int w = 0; w < 32; w++) {
        const int jl = jh + w * 2;
        const int j  = jb + jl;
        const int cp = (j < 192) ? 2 * j : 2 * (j - 192) + 1;
        WT[((long)k * 384 + cp) * 128 + rl] = (f16)T[jl][rl];
    }
}

// WupT[(k*384+cp)][r] (r<192), highway folded.
__global__ void packupT_k(const float* __restrict__ Wup, const float* __restrict__ hw,
                          f16* __restrict__ WT)
{
    __shared__ float T[64][65];
    const int jb = blockIdx.x * 64, rb = blockIdx.y * 64, k = blockIdx.z;
    const float hwk = hw[k];
    const int lc = threadIdx.x & 63, lw = threadIdx.x >> 6;
    #pragma unroll
    for (int w = 0; w < 16; w++) {
        const int r = rb + lw + w * 4;
        T[lw + w * 4][lc] = Wup[(long)r * 4608 + k * 384 + jb + lc] * hwk;
    }
    __syncthreads();
    #pragma unroll
    for (int w = 0; w < 16; w++) {
        const int jl = lw + w * 4;
        const int j  = jb + jl;
        const int cp = (j < 192) ? 2 * j : 2 * (j - 192) + 1;
        WT[((long)k * 384 + cp) * 192 + rb + lc] = (f16)T[lc][jl];
    }
}

// WoutT[c][r] (c<768, r<2304) from W_out[2304][768].
__global__ void packoutT_k(const float* __restrict__ Wout, f16* __restrict__ WT)
{
    __shared__ float T[64][65];
    const int rb = blockIdx.x * 64, cb = blockIdx.y * 64;
    const int lc = threadIdx.x & 63, lw = threadIdx.x >> 6;
    #pragma unroll
    for (int w = 0; w < 16; w++) {
        const int r = lw + w * 4;
        T[r][lc] = Wout[(long)(rb + r) * 768 + (cb + lc)];
    }
    __syncthreads();
    #pragma unroll
    for (int w = 0; w < 16; w++) {
        const int c = lw + w * 4;
        WT[(long)(cb + c) * 2304 + rb + lc] = (f16)T[lc][c];
    }
}

// ---------------------------------------------------------------------------
// Fused scan with rolling conv window: Pall rows are [780 Z | 12 G] f32
// (stride PS2_); only row l is loaded per step, taps l-3..l-1 live in regs
// (identical arithmetic order to the 4-tap reload — bit-identical numerics).
// Q read from f16 Qh plane (pass3). Pass1: per-(chunk,k) sums into
// csum[z][k][ch][129]. Pass3: prefix init, emit OUTAh f16.
// grid (CH2_, K_, nb), 64 threads (lane = h).
// ---------------------------------------------------------------------------
template<bool FINAL>
__global__ __launch_bounds__(64) void scan_k(
    const float* __restrict__ Pb, const f16* __restrict__ Qhb,
    const float* __restrict__ convk,
    const float* __restrict__ theta, const float* __restrict__ decay,
    const float* __restrict__ ssc, const float* __restrict__ nsc,
    const float* __restrict__ bg, float* __restrict__ csumb,
    f16* __restrict__ OUTAhb)
{
    const int zb = blockIdx.z;
    const float* P  = Pb + (long)zb * L_ * PS2_;
    const f16* Qh   = FINAL ? Qhb + (long)zb * L_ * 768 : nullptr;
    float* csum     = csumb + (long)zb * K_ * CH2_ * 129;
    f16* OUTAh      = FINAL ? OUTAhb + (long)zb * L_ * 1536 : nullptr;

    const int ch = blockIdx.x, k = blockIdx.y, h = threadIdx.x;
    const int col = k * 64 + h, scol = 768 + k;
    const int l0 = ch * CL2_;

    const float ck0 = convk[col],  ck1 = convk[ZC_ + col];
    const float ck2 = convk[2 * ZC_ + col], ck3 = convk[3 * ZC_ + col];
    const float cs0 = convk[scol], cs1 = convk[ZC_ + scol];
    const float cs2 = convk[2 * ZC_ + scol], cs3 = convk[3 * ZC_ + scol];

    const float th    = softplusf(theta[k * 64 + h]) + 0.001f;
    const float slope = softplusf(decay[k]);
    const float sscal = ssc[k];
    const float ns    = FINAL ? nsc[k * 64 + h] : 0.f;
    const float bgk   = FINAL ? bg[k] : 0.f;
    const int   kq    = k >> 1;

    const long cb = ((long)k * CH2_ + ch) * 129;
    float dacc = 0.f, racc = 0.f, iacc = 0.f;
    if (FINAL) { dacc = csum[cb]; racc = csum[cb + 1 + h]; iacc = csum[cb + 65 + h]; }

    // rolling window init: z[l0-3..l0-1], s[l0-3..l0-1] (0 before row 0)
    float z0, z1, z2, s0, s1, s2;
    {
        const int a = l0 - 3, b2 = l0 - 2, c = l0 - 1;
        z0 = (a  >= 0) ? P[(long)a  * PS2_ + col]  : 0.f;
        z1 = (b2 >= 0) ? P[(long)b2 * PS2_ + col]  : 0.f;
        z2 = (c  >= 0) ? P[(long)c  * PS2_ + col]  : 0.f;
        s0 = (a  >= 0) ? P[(long)a  * PS2_ + scol] : 0.f;
        s1 = (b2 >= 0) ? P[(long)b2 * PS2_ + scol] : 0.f;
        s2 = (c  >= 0) ? P[(long)c  * PS2_ + scol] : 0.f;
    }

    for (int p = 0; p < CL2_; p++) {
        const int l = l0 + p;
        const float z3 = P[(long)l * PS2_ + col];
        const float s3 = P[(long)l * PS2_ + scol];
        const float kv = ck0 * z0 + ck1 * z1 + ck2 * z2 + ck3 * z3;
        const float sr = cs0 * s0 + cs1 * s1 + cs2 * s2 + cs3 * s3;
        const float lp = fminf(fmaxf(sscal * sr, -20.f), 20.f);
        const float pw = __expf(lp - slope * (float)(L_ - 1 - l));
        const float phi = tanhf(kv) * th;
        float sn, cn; __sincosf(phi, &sn, &cn);
        dacc += pw; racc += kv * pw * cn; iacc += kv * pw * sn;

        if (FINAL) {
            const float invd = 1.f / fmaxf(dacc, 1e-4f);
            const float sre = racc * invd, sim = iacc * invd;
            const float qr = (float)Qh[(long)l * 768 + (kq * 64 + h) * 2];
            const float qi = (float)Qh[(long)l * 768 + (kq * 64 + h) * 2 + 1];
            const float gate = sigmoidf(P[(long)l * PS2_ + QOFF_ + k] + bgk);
            const float s2g = ns * gate;
            f16* orow = OUTAh + (long)l * 1536 + k * 128;
            orow[h]      = (f16)((sre * qr + sim * qi) * s2g);
            orow[64 + h] = (f16)((sim * qr - sre * qi) * s2g);
        }
        z0 = z1; z1 = z2; z2 = z3;
        s0 = s1; s1 = s2; s2 = s3;
    }
    if (!FINAL) {
        if (h == 0) csum[cb] = dacc;
        csum[cb + 1 + h]  = racc;
        csum[cb + 65 + h] = iacc;
    }
}

// exclusive prefix over the 128 chunks, per (batch=blockIdx.y, k, entry).
__global__ void scan2_k(float* __restrict__ csumb)
{
    float* csum = csumb + (long)blockIdx.y * K_ * CH2_ * 129;
    const int k = blockIdx.x;
    const int t = threadIdx.x;
    if (t >= 129) return;
    float run = 0.f;
    for (int g = 0; g < CH2_; g += 32) {
        float v[32];
        #pragma unroll
        for (int c = 0; c < 32; c++)
            v[c] = csum[((long)k * CH2_ + g + c) * 129 + t];
        #pragma unroll
        for (int c = 0; c < 32; c++) { const float x = v[c]; v[c] = run; run += x; }
        #pragma unroll
        for (int c = 0; c < 32; c++)
            csum[((long)k * CH2_ + g + c) * 129 + t] = v[c];
    }
}

// ---------------------------------------------------------------------------
extern "C" void kernel_launch(void* const* d_in, const int* in_sizes, int n_in,
                              void* d_out, int out_size, void* d_ws, size_t ws_size,
                              hipStream_t stream)
{
    float* out = (float*)d_out;   // f32 output (verified r8)
    const dim3 blk(256);

    // tripwire: input ordering/sizes
    const int expSz[16] = {12582912, 599040, 3120, 589824, 768, 12, 12,
                           294912, 294912, 768, 9216, 12, 147456, 884736,
                           12, 1769472};
    int bad = -1;
    if (n_in != 16) bad = 99;
    else { for (int i = 0; i < 16; i++) if (in_sizes[i] != expSz[i]) { bad = i; break; } }
    if (out_size != 12582912 && bad < 0) bad = 98;
    if (bad >= 0) {
        fillf_k<<<dim3(2048), blk, 0, stream>>>(out, out_size, 3000.f + bad);
        return;
    }

    const float* x     = (const float*)d_in[0];
    const float* W_mem = (const float*)d_in[1];
    const float* convk = (const float*)d_in[2];
    const float* W_q   = (const float*)d_in[3];
    const float* theta = (const float*)d_in[4];
    const float* decay = (const float*)d_in[5];
    const float* ssc   = (const float*)d_in[6];
    const float* W_re  = (const float*)d_in[7];
    const float* W_im  = (const float*)d_in[8];
    const float* nsc   = (const float*)d_in[9];
    const float* Wg    = (const float*)d_in[10];
    const float* bg    = (const float*)d_in[11];
    const float* W_dn  = (const float*)d_in[12];
    const float* W_up  = (const float*)d_in[13];
    const float* hw    = (const float*)d_in[14];
    const float* W_out = (const float*)d_in[15];

    // ---- workspace ladder: cfg0 full-batch; cfg1 per-batch acts + full yah;
    //      cfg2 everything per-batch.
    size_t o[13];
    auto plan = [&](bool fullP, bool fullY, size_t* oo) -> size_t {
        const long rp = fullP ? (long)B_ * L_ : L_;
        const long ry = fullY ? (long)B_ * L_ : L_;
        size_t off = 0;
        auto al = [&](size_t bytes) {
            size_t cur = off; off = (off + bytes + 255) & ~(size_t)255; return cur;
        };
        oo[0]  = al(4);                                   // md
        oo[1]  = al((size_t)B_ * K_ * CH2_ * 129 * 4);    // csum (all batches)
        oo[2]  = al((size_t)rp * 768 * 2);                // xh (f16)
        oo[3]  = al((size_t)rp * PS2_ * 4);               // Pall (f32, Z|G)
        oo[4]  = al((size_t)rp * 768 * 2);                // Qh (f16)
        oo[5]  = al((size_t)rp * 1536 * 2);               // OUTAh (f16)
        oo[6]  = al((size_t)rp * 192 * 2);                // LATh (f16)
        oo[7]  = al((size_t)ry * 2304 * 2);               // yah (f16)
        oo[8]  = al((size_t)WPAD_ * 768 * 2);             // WallT
        oo[9]  = al((size_t)K_ * 384 * 128 * 2);          // WriT
        oo[10] = al((size_t)4608 * 192 * 2);              // WupT
        oo[11] = al((size_t)768 * 2304 * 2);              // WoutT
        return off;
    };
    const int nCfg = 3;
    const bool cfgP[nCfg] = {true, false, false};
    const bool cfgY[nCfg] = {true, true,  false};
    int cfg = -1;
    for (int c = 0; c < nCfg; c++) {
        size_t t = plan(cfgP[c], cfgY[c], o);
        if (t + 4096 <= ws_size) { cfg = c; break; }
    }
    if (cfg < 0) {
        fillf_k<<<dim3(2048), blk, 0, stream>>>(out, (long)out_size, 1000.f);
        return;
    }
    const bool FULLP = cfgP[cfg], FULLY = cfgY[cfg];

    char* ws = (char*)d_ws;
    int*   md    = (int*)(ws + o[0]);
    float* csum  = (float*)(ws + o[1]);
    f16*   xh    = (f16*)(ws + o[2]);
    float* Pall  = (float*)(ws + o[3]);
    f16*   Qh    = (f16*)(ws + o[4]);
    f16*   OUTAh = (f16*)(ws + o[5]);
    f16*   LATh  = (f16*)(ws + o[6]);
    f16*   yah   = (f16*)(ws + o[7]);
    f16*   WallT = (f16*)(ws + o[8]);
    f16*   WriT  = (f16*)(ws + o[9]);
    f16*   WupT  = (f16*)(ws + o[10]);
    f16*   WoutT = (f16*)(ws + o[11]);

    probe_k<<<dim3(1), dim3(64), 0, stream>>>((const unsigned*)ssc, md);
    packwallT_k<<<dim3(12, 28), blk, 0, stream>>>(W_mem, W_q, Wg, W_dn, WallT);
    packriT_k<<<dim3(6, 12), blk, 0, stream>>>(W_re, W_im, WriT);
    packupT_k<<<dim3(6, 3, 12), blk, 0, stream>>>(W_up, hw, WupT);
    packoutT_k<<<dim3(36, 12), blk, 0, stream>>>(W_out, WoutT);

    const int nb    = FULLP ? 1 : B_;
    const long Mr   = FULLP ? (long)B_ * L_ : L_;
    const int nTm   = (int)(Mr / 128);
    const int zGrid = FULLP ? B_ : 1;

    for (int b = 0; b < nb; b++) {
        const float* xb = x + (long)b * L_ * 768;

        // pack x -> f16 (vectorized), then merged projection GEMM:
        // Z|G -> Pall f32, Q -> Qh f16, LAT -> LATh f16 (epilogue routing)
        packxh_k<<<dim3(2048), blk, 0, stream>>>(xb, xh, Mr * 768 / 8);
        gemmh_k<<<dim3(14 * nTm), blk, 0, stream>>>(
            xh, WallT, Pall, LATh, Qh, 1752, 768, 768, 768, PS2_, 14);

        // fused chunked scan (rolling conv window), 3 passes -> OUTAh (f16)
        scan_k<false><<<dim3(CH2_, K_, zGrid), dim3(64), 0, stream>>>(
            Pall, nullptr, convk, theta, decay, ssc, nsc, bg, csum, nullptr);
        scan2_k<<<dim3(K_, zGrid), dim3(192), 0, stream>>>(csum);
        scan_k<true><<<dim3(CH2_, K_, zGrid), dim3(64), 0, stream>>>(
            Pall, Qh, convk, theta, decay, ssc, nsc, bg, csum, OUTAh);

        // fused stage 3+4 -> ya (f16)
        f16* yd = (FULLY && !FULLP) ? yah + (long)b * L_ * 2304 : yah;
        stage34h_k<<<dim3(36 * nTm), blk, 0, stream>>>(
            OUTAh, LATh, WriT, WupT, yd);

        if (!FULLY) {
            gemmh_k<<<dim3(6 * nTm), blk, 0, stream>>>(
                yah, WoutT, out + (long)b * L_ * 768, (f16*)nullptr, (f16*)nullptr,
                768, 2304, 2304, 2304, 768, 6);
        }
    }

    if (FULLY) {
        // one out-GEMM over all batches: (B*L) x 768, Kd=2304
        gemmh_k<<<dim3(6 * (int)((long)B_ * L_ / 128)), blk, 0, stream>>>(
            yah, WoutT, out, (f16*)nullptr, (f16*)nullptr, 768, 2304, 2304, 2304, 768, 6);
    }

    guard_k<<<dim3(2048), blk, 0, stream>>>(md, out, (long)out_size);
}